// Round 15
// baseline (115.210 us; speedup 1.0000x reference)
//
#include <hip/hip_runtime.h>
#include <hip/hip_bf16.h>

#define BATCH 64
#define IN_CH 128
#define ILEN  512
#define OLEN  505
#define OCH   128
#define KDIM  1024    // IN_CH * 8
#define BK    32      // K per chunk
#define NCHK  32      // KDIM / BK
#define NWG   OLEN

typedef float  f32x4  __attribute__((ext_vector_type(4)));
typedef short  bf16x8 __attribute__((ext_vector_type(8)));
typedef unsigned short u16x8 __attribute__((ext_vector_type(8)));
typedef u16x8 u16x8a __attribute__((aligned(4)));

__device__ __forceinline__ unsigned short f2bfu(float f) {
  union { __hip_bfloat16 h; unsigned short s; } u;
  u.h = __float2bfloat16(f);
  return u.s;
}
__device__ __forceinline__ short f2bf(float f) { return (short)f2bfu(f); }
__device__ __forceinline__ float bf2f(unsigned short s) {
  union { unsigned int u; float f; } u;
  u.u = ((unsigned int)s) << 16;
  return u.f;
}

// ---- pre-pass (R11-verified): x fp32 -> bf16 dual-shifted copies ----
__global__ __launch_bounds__(256) void lc1d_cvt(const float* __restrict__ x,
                                                unsigned short* __restrict__ xbe,
                                                unsigned short* __restrict__ xbo) {
  const int gid = blockIdx.x * 256 + threadIdx.x;
  const int row = gid >> 6;
  const int t8  = (gid & 63) << 3;
  const float* src = x + (size_t)row * ILEN + t8;
  const f32x4 v0 = *reinterpret_cast<const f32x4*>(src);
  const f32x4 v1 = *reinterpret_cast<const f32x4*>(src + 4);
  const float e8 = (t8 + 8 < ILEN) ? src[8] : 0.f;
  u16x8 e, o;
#pragma unroll
  for (int j = 0; j < 4; ++j) { e[j] = f2bfu(v0[j]); e[4 + j] = f2bfu(v1[j]); }
  o[0] = e[1]; o[1] = e[2]; o[2] = e[3];
  o[3] = e[4]; o[4] = e[5]; o[5] = e[6]; o[6] = e[7];
  o[7] = f2bfu(e8);
  *reinterpret_cast<u16x8*>(xbe + (size_t)row * ILEN + t8) = e;
  *reinterpret_cast<u16x8*>(xbo + (size_t)row * ILEN + t8) = o;
}

// ---- main: ring-4 Bs (probe-verified slack) + slim A + compressed consume ----
// Steady state has ZERO explicit vmcnt: issue order {loadA(kc+2); stageB(kc+3)}
// makes writeA's compiler wait (vmcnt(9): retires A1(kc+1) and the OLDER
// B4(kc+1)) the only wait. B(kc+1) slack = 2 full iterations (probe config).
// DS ops/thread/iter: 8 b128 reads + 1 b128 write (R14: ~16 normalized).
template <bool USE_TMP>
__global__ __launch_bounds__(256, 2) void lc1d_main(
    const unsigned short* __restrict__ xbe, const unsigned short* __restrict__ xbo,
    const float* __restrict__ w, const float* __restrict__ bias,
    void* __restrict__ outp) {
  const int orig = blockIdx.x;
  const int xcd = orig & 7, idx = orig >> 3;
  const int q = NWG / 8, rm = NWG % 8;
  const int l = (xcd < rm ? xcd * (q + 1) : rm * (q + 1) + (xcd - rm) * q) + idx;

  const int tid  = threadIdx.x;
  const int lane = tid & 63;
  const int wn   = tid >> 6;
  const int r    = lane & 15;
  const int h    = lane >> 4;

  __shared__ float Bs[4][2][BK * 64];   // 64 KB: [slot][oh][o*32 + c*4], c'=c^(o&7)
  __shared__ short As[2][BATCH * BK];   // 8 KB:  [buf][b*32 + c*8],      c'=c^(b&3)

  f32x4 acc[2][4];
#pragma unroll
  for (int oh = 0; oh < 2; ++oh)
#pragma unroll
    for (int m = 0; m < 4; ++m) acc[oh][m] = (f32x4){0.f, 0.f, 0.f, 0.f};

  const float* __restrict__ wl = w + (size_t)l * (OCH * KDIM);
  const unsigned short* __restrict__ xw =
      ((l & 1) ? xbo : xbe) + (size_t)(l & ~1);

  // B staging: op it: oh=it>>1, o_local=(it&1)*32+(tid>>3), c'=tid&7
  const int sor = tid >> 3;          // 0..31 row part
  const int scp = tid & 7;           // dest 16B chunk
  auto stageB = [&](int slot, int kc) {
#pragma unroll
    for (int it = 0; it < 4; ++it) {
      const int oh = it >> 1;
      const int ol = (it & 1) * 32 + sor;
      const float* src = wl + (size_t)(oh * 64 + ol) * KDIM + kc * BK +
                         (scp ^ (ol & 7)) * 4;
      __builtin_amdgcn_global_load_lds(
          (const __attribute__((address_space(1))) void*)src,
          (__attribute__((address_space(3))) void*)&Bs[slot][oh][ol * 32 + scp * 4],
          16, 0, 0);
    }
  };

  // A staging: thread (bA, iw): i = kc*4+iw, one u16x8 load + one b128 write
  const int bA = tid & 63;
  const int iw = tid >> 6;
  u16x8 vaE, vaO;   // chunk-parity regs: chunk c lives in (c&1 ? vaO : vaE)
  auto loadA = [&](u16x8& va, int kc) {
    va = *reinterpret_cast<const u16x8a*>(
        xw + (size_t)(bA * IN_CH + kc * 4 + iw) * ILEN);
  };
  auto writeA = [&](const u16x8& va, int buf) {
    *reinterpret_cast<u16x8*>(&As[buf][bA * 32 + ((iw ^ (bA & 3)) << 3)]) = va;
  };

  auto computeBoth = [&](int slot, int abuf) {
    const int o2  = wn * 16 + r;
    const int swb = o2 & 7;
    bf16x8 af[4];
#pragma unroll
    for (int mt = 0; mt < 4; ++mt) {
      const int b = mt * 16 + r;
      af[mt] = *reinterpret_cast<const bf16x8*>(
          &As[abuf][b * 32 + ((h ^ (b & 3)) << 3)]);
    }
    const f32x4 b0lo = *reinterpret_cast<const f32x4*>(
        &Bs[slot][0][o2 * 32 + (((2 * h) ^ swb) << 2)]);
    const f32x4 b0hi = *reinterpret_cast<const f32x4*>(
        &Bs[slot][0][o2 * 32 + (((2 * h + 1) ^ swb) << 2)]);
    const f32x4 b1lo = *reinterpret_cast<const f32x4*>(
        &Bs[slot][1][o2 * 32 + (((2 * h) ^ swb) << 2)]);
    const f32x4 b1hi = *reinterpret_cast<const f32x4*>(
        &Bs[slot][1][o2 * 32 + (((2 * h + 1) ^ swb) << 2)]);
    bf16x8 bf0, bf1;
#pragma unroll
    for (int j = 0; j < 4; ++j) {
      bf0[j] = f2bf(b0lo[j]); bf0[4 + j] = f2bf(b0hi[j]);
      bf1[j] = f2bf(b1lo[j]); bf1[4 + j] = f2bf(b1hi[j]);
    }
#pragma unroll
    for (int mt = 0; mt < 4; ++mt)
      acc[0][mt] = __builtin_amdgcn_mfma_f32_16x16x32_bf16(af[mt], bf0, acc[0][mt], 0, 0, 0);
#pragma unroll
    for (int mt = 0; mt < 4; ++mt)
      acc[1][mt] = __builtin_amdgcn_mfma_f32_16x16x32_bf16(af[mt], bf1, acc[1][mt], 0, 0, 0);
  };

  // ---- prologue: A(0)->As[0]; B(0),B(1),B(2) staged; A(1) in vaO ----
  loadA(vaE, 0);        // A1(0) oldest
  stageB(0, 0);         // B4(0)
  stageB(1, 1);         // B4(1)
  stageB(2, 2);         // B4(2)
  writeA(vaE, 0);       // compiler wait vmcnt(12): retires A1(0); B12 fly
  loadA(vaO, 1);        // -> 13 outstanding
  asm volatile("s_waitcnt vmcnt(9) lgkmcnt(0)" ::: "memory");  // retire B4(0)
  __builtin_amdgcn_sched_barrier(0);
  __builtin_amdgcn_s_barrier();
  __builtin_amdgcn_sched_barrier(0);

  // iter kc: issue {loadA(kc+2), stageB(kc+3)}; compute(kc); writeA(kc+1); barrier
  auto step = [&](int kc, u16x8& aL /*<-chunk kc+2*/, u16x8& aW /*=chunk kc+1*/) {
    if (kc + 2 < NCHK) loadA(aL, kc + 2);
    if (kc + 3 < NCHK) stageB((kc + 3) & 3, kc + 3);
    __builtin_amdgcn_sched_barrier(0);
    computeBoth(kc & 3, kc & 1);
    if (kc + 1 < NCHK) {
      writeA(aW, (kc + 1) & 1);   // implicit vmcnt(9): retires A1(kc+1)+B4(kc+1)
      asm volatile("s_waitcnt lgkmcnt(0)" ::: "memory");   // NO vmcnt here
      __builtin_amdgcn_sched_barrier(0);
      __builtin_amdgcn_s_barrier();
      __builtin_amdgcn_sched_barrier(0);
    }
  };

  for (int kc = 0; kc < NCHK; kc += 2) {
    step(kc, vaE, vaO);       // even kc: chunk kc+2 -> vaE; write chunk kc+1 (vaO)
    step(kc + 1, vaO, vaE);   // odd  kc: chunk kc+3 -> vaO; write chunk kc+2 (vaE)
  }

  // ---- epilogue (R14-verified): C/D col(o)=lane&15, row(b)=(lane>>4)*4+j ----
#pragma unroll
  for (int oh = 0; oh < 2; ++oh) {
    const int og = oh * 64 + wn * 16 + r;
    if (USE_TMP) {
      unsigned short* t = (unsigned short*)outp + (size_t)l * (BATCH * OCH) + og;
#pragma unroll
      for (int mt = 0; mt < 4; ++mt)
#pragma unroll
        for (int j = 0; j < 4; ++j) {
          const int b = mt * 16 + h * 4 + j;
          t[(size_t)b * OCH] = f2bfu(acc[oh][mt][j]);
        }
    } else {
      const float bv = bias[og * OLEN + l];
#pragma unroll
      for (int mt = 0; mt < 4; ++mt)
#pragma unroll
        for (int j = 0; j < 4; ++j) {
          const int b = mt * 16 + h * 4 + j;
          ((float*)outp)[(size_t)b * (OCH * OLEN) + (size_t)og * OLEN + l] =
              acc[oh][mt][j] + bv;
        }
    }
  }
}

// tmp(bf16)[l][b][o] -> out(f32)[b][o][l] (+bias)
__global__ __launch_bounds__(256) void lc1d_tr(const unsigned short* __restrict__ tmp,
                                               const float* __restrict__ bias,
                                               float* __restrict__ out) {
  const int l0  = blockIdx.x * 64;
  const int bo0 = blockIdx.y * 64;
  const int tid = threadIdx.x;
  __shared__ float t[64][65];

  const int boj = tid & 63, lq = tid >> 6;
#pragma unroll
  for (int rr = 0; rr < 16; ++rr) {
    const int li = rr * 4 + lq;
    const int l  = l0 + li;
    if (l < OLEN)
      t[li][boj] = bf2f(tmp[(size_t)l * (BATCH * OCH) + bo0 + boj]);
  }
  __syncthreads();
  const int lj = tid & 63, bq = tid >> 6;
  const int l  = l0 + lj;
#pragma unroll
  for (int rr = 0; rr < 16; ++rr) {
    const int bl = rr * 4 + bq;
    const int bo = bo0 + bl;
    if (l < OLEN) {
      const int oc = bo & (OCH - 1);
      out[(size_t)bo * OLEN + l] = t[lj][bl] + bias[oc * OLEN + l];
    }
  }
}

// fallback: naive fp32 (only if ws unexpectedly tiny)
__global__ void lc1d_naive(const float* __restrict__ x, const float* __restrict__ w,
                           const float* __restrict__ bias, float* __restrict__ out) {
  const int l = blockIdx.x, o = blockIdx.y, b = threadIdx.x;
  const float* wr = w + ((size_t)l * OCH + o) * KDIM;
  const float* xr = x + (size_t)b * (IN_CH * ILEN);
  float s = 0.f;
  for (int i = 0; i < IN_CH; ++i)
#pragma unroll
    for (int k = 0; k < 8; ++k) s += xr[i * ILEN + l + k] * wr[i * 8 + k];
  out[((size_t)b * OCH + o) * OLEN + l] = s + bias[o * OLEN + l];
}

extern "C" void kernel_launch(void* const* d_in, const int* in_sizes, int n_in,
                              void* d_out, int out_size, void* d_ws, size_t ws_size,
                              hipStream_t stream) {
  const float* x    = (const float*)d_in[0];
  const float* w    = (const float*)d_in[1];
  const float* bias = (const float*)d_in[2];
  float* out        = (float*)d_out;

  const size_t TMPB = (size_t)OLEN * BATCH * OCH * sizeof(unsigned short); // 8.3 MB
  const size_t off1 = (TMPB + 255) & ~(size_t)255;
  const size_t XBB  = (size_t)BATCH * IN_CH * ILEN * sizeof(short);       // 8.4 MB
  const size_t need = off1 + 2 * XBB;                                     // ~25 MB

  if (ws_size >= need) {
    unsigned short* tmp = (unsigned short*)d_ws;
    unsigned short* xbe = (unsigned short*)((char*)d_ws + off1);
    unsigned short* xbo = (unsigned short*)((char*)d_ws + off1 + XBB);
    lc1d_cvt<<<dim3(2048), 256, 0, stream>>>(x, xbe, xbo);
    lc1d_main<true><<<dim3(NWG), 256, 0, stream>>>(xbe, xbo, w, bias, (void*)tmp);
    lc1d_tr<<<dim3(8, 128), 256, 0, stream>>>(tmp, bias, out);
  } else {
    lc1d_naive<<<dim3(OLEN, OCH), BATCH, 0, stream>>>(x, w, bias, out);
  }
}